// Round 3
// baseline (449.672 us; speedup 1.0000x reference)
//
#include <hip/hip_runtime.h>

#define NN 4096
#define FF 256
#define EE 65536
#define MAXDEG 128
#define MAXEPR 512
#define NCAND 2048
#define LLEN 160

__device__ __forceinline__ int wred_sum(int v) {
#pragma unroll
    for (int o = 32; o >= 1; o >>= 1) v += __shfl_xor(v, o);
    return v;
}

// ---------------------------------------------------------------------------
// K1: per-row edge-id lists only (no dense A)
// ---------------------------------------------------------------------------
__global__ void k_scatter(const int* __restrict__ ei, int* __restrict__ ecnt,
                          int* __restrict__ elist) {
    int e = blockIdx.x * blockDim.x + threadIdx.x;
    if (e >= EE) return;
    int r = ei[e];
    int p = atomicAdd(&ecnt[r], 1);
    if (p < MAXEPR) elist[r * MAXEPR + p] = e;
}

// ---------------------------------------------------------------------------
// K2: build CSR row directly from edge list (wave per row): dedup cols,
// sum dup weights, clamp to 1, drop diagonal. Also computes sq[row].
// ---------------------------------------------------------------------------
__global__ void k_build(const int* __restrict__ ei, const float* __restrict__ ew,
                        const int* __restrict__ ecnt, const int* __restrict__ elist,
                        const float* __restrict__ X,
                        unsigned short* __restrict__ ccol, float* __restrict__ cval,
                        int* __restrict__ deg, double* __restrict__ sq) {
    __shared__ unsigned short lcol[4][LLEN];
    __shared__ float lval[4][LLEN];
    const int wv = threadIdx.x >> 6;
    const int lane = threadIdx.x & 63;
    const int u = blockIdx.x * 4 + wv;
    if (u >= NN) return;
    const unsigned long long lmask = (1ull << lane) - 1ull;

    int ne = ecnt[u]; if (ne > MAXEPR) ne = MAXEPR;
    int len = 0;                                   // wave-uniform list length
    for (int base = 0; base < ne; base += 64) {
        int i = base + lane;
        bool act = (i < ne);
        int e = act ? elist[u * MAXEPR + i] : 0;
        int c = act ? ei[EE + e] : -1;
        if (c == u) { act = false; c = -1; }       // diagonal irrelevant
        float w = act ? ew[e] : 0.f;
        // within-chunk leader election + duplicate sum (64-step shfl scan)
        float sum = 0.f;
        bool leader = act;
        for (int j = 0; j < 64; ++j) {
            int cj = __shfl(c, j);
            float wj = __shfl(w, j);
            if (act && cj == c) {
                sum += wj;
                if (j < lane) leader = false;
            }
        }
        if (base == 0) {
            unsigned long long m = __ballot(leader);
            int pos = __popcll(m & lmask);
            if (leader && pos < LLEN) { lcol[wv][pos] = (unsigned short)c; lval[wv][pos] = sum; }
            len = __popcll(m);
        } else {
            int found = -1;
            if (leader) {
                for (int t = 0; t < len; ++t)
                    if ((int)lcol[wv][t] == c) { found = t; break; }
            }
            if (leader && found >= 0) lval[wv][found] += sum;
            unsigned long long m = __ballot(leader && found < 0);
            int pos = len + __popcll(m & lmask);
            if (leader && found < 0 && pos < LLEN) { lcol[wv][pos] = (unsigned short)c; lval[wv][pos] = sum; }
            len += __popcll(m);
        }
    }
    // write CSR (cap at MAXDEG; deg = true dedup count)
    for (int t = lane; t < len && t < MAXDEG; t += 64) {
        ccol[u * MAXDEG + t] = lcol[wv][t];
        cval[u * MAXDEG + t] = fminf(lval[wv][t], 1.f);
    }
    if (lane == 0) deg[u] = len;

    // sq[u] = sum X[u]^2 in f64
    float4 x4 = ((const float4*)(X + (size_t)u * FF))[lane];
    double s = (double)x4.x * x4.x + (double)x4.y * x4.y +
               (double)x4.z * x4.z + (double)x4.w * x4.w;
#pragma unroll
    for (int o = 32; o >= 1; o >>= 1) s += __shfl_xor(s, o);
    if (lane == 0) sq[u] = s;
}

// ---------------------------------------------------------------------------
// K3: d_thres = mean(deg) + 2*std(deg), single block
// ---------------------------------------------------------------------------
__global__ void k_stats(const int* __restrict__ deg, double* __restrict__ thres) {
    __shared__ double sd[256], sd2[256];
    int t = threadIdx.x;
    double s = 0, s2 = 0;
    for (int i = t; i < NN; i += 256) {
        double d = (double)deg[i];
        s += d; s2 += d * d;
    }
    sd[t] = s; sd2[t] = s2;
    __syncthreads();
    for (int o = 128; o >= 1; o >>= 1) {
        if (t < o) { sd[t] += sd[t + o]; sd2[t] += sd2[t + o]; }
        __syncthreads();
    }
    if (t == 0) {
        double mean = sd[0] / NN;
        double var = sd2[0] / NN - mean * mean;
        if (var < 0) var = 0;
        thres[0] = mean + 2.0 * sqrt(var);
    }
}

// ---------------------------------------------------------------------------
// K4: per-row main kernel
// ---------------------------------------------------------------------------
__launch_bounds__(256, 5)
__global__ void k_main(const int* __restrict__ ei, const float* __restrict__ ew,
                       const float* __restrict__ X, const float* __restrict__ th1p,
                       const float* __restrict__ th2p,
                       const unsigned short* __restrict__ ccol,
                       const float* __restrict__ cval, const int* __restrict__ deg,
                       const int* __restrict__ ecnt, const int* __restrict__ elist,
                       const double* __restrict__ sq, const double* __restrict__ thresp,
                       float* __restrict__ out) {
    __shared__ float acc[NN];              // A2 row values (16KB)
    __shared__ float Xu[FF];               // 1KB
    __shared__ unsigned short cidx[NCAND]; // 4KB
    __shared__ float cdist[NCAND];         // 8KB
    __shared__ unsigned short Aucol[MAXDEG];
    __shared__ float Auval[MAXDEG];
    __shared__ int ncand;

    const int u = blockIdx.x;
    const int tid = threadIdx.x;
    const int lane = tid & 63;
    const int wave = tid >> 6;
    const unsigned long long lmask = (1ull << lane) - 1ull;

    const int du = deg[u];
    const int dul = min(du, MAXDEG);
    for (int i = tid; i < NN; i += 256) acc[i] = 0.f;
    if (tid < FF / 4)
        ((float4*)Xu)[tid] = ((const float4*)(X + (size_t)u * FF))[tid];
    if (tid >= 128 && tid - 128 < dul) {
        Aucol[tid - 128] = ccol[u * MAXDEG + tid - 128];
        Auval[tid - 128] = cval[u * MAXDEG + tid - 128];
    }
    if (tid == 0) ncand = 0;
    __syncthreads();

    // --- build A2 row: A' = A + I; acc[v] += A'[u][k]*A'[k][v] ---
    for (int kk = wave; kk <= dul; kk += 4) {
        int k; float wuk;
        if (kk == dul) { k = u; wuk = 1.f; }           // self term A'[u][u]=1
        else { k = Aucol[kk]; wuk = Auval[kk]; }
        int dkl = min(deg[k], MAXDEG);
        for (int j = lane; j <= dkl; j += 64) {
            int v; float wkv;
            if (j == dkl) { v = k; wkv = 1.f; }        // self term A'[k][k]=1
            else { v = ccol[k * MAXDEG + j]; wkv = cval[k * MAXDEG + j]; }
            atomicAdd(&acc[v], wuk * wkv);
        }
    }
    __syncthreads();
    if (tid == 0) acc[u] = 0.f;                        // zero diag of A2
    __syncthreads();

    // --- compact 2-hop candidates (ballot-aggregated) ---
    for (int i = tid; i < NN; i += 256) {
        bool nzf = (acc[i] != 0.f);
        unsigned long long m = __ballot(nzf);
        int base = 0;
        if (lane == 0 && m) base = atomicAdd(&ncand, __popcll(m));
        base = __shfl(base, 0);
        int pos = base + __popcll(m & lmask);
        if (nzf && pos < NCAND) cidx[pos] = (unsigned short)i;
    }
    __syncthreads();
    const int Dr = ncand;
    const int Drs = min(Dr, NCAND);

    // --- distances: 16 candidates x 4 lanes per wave (coalesced gathers) ---
    const double squ = sq[u];
    const int sub = lane & 3;
    for (int c0 = wave * 16; c0 < Drs; c0 += 64) {
        int ci = c0 + (lane >> 2);
        bool live = (ci < Drs);
        int v = live ? cidx[ci] : 0;
        const float4* Xv = (const float4*)(X + (size_t)v * FF);
        double s = 0.0;
#pragma unroll
        for (int i = 0; i < 16; ++i) {
            float4 a = Xv[i * 4 + sub];
            float4 b = ((const float4*)Xu)[i * 4 + sub];
            s += (double)a.x * b.x + (double)a.y * b.y +
                 (double)a.z * b.z + (double)a.w * b.w;
        }
        s += __shfl_xor(s, 1);
        s += __shfl_xor(s, 2);
        if (live && sub == 0)
            cdist[ci] = (float)(squ + sq[v] - 2.0 * s);
    }
    __syncthreads();

    // --- per-edge output: one WAVE per edge ---
    const int D = du;
    const bool highD = ((double)D > thresp[0]);
    const int nz = Dr - 2 * D;                         // nz_sel
    const float th1 = th1p[0], th2 = th2p[0];
    int ne = ecnt[u]; if (ne > MAXEPR) ne = MAXEPR;
    for (int idx = wave; idx < ne; idx += 4) {
        int e = elist[u * MAXEPR + idx];
        int v = ei[EE + e];                            // wave-uniform
        float w = ew[e];
        float a2v = acc[v];
        // av = A[u][v] via LDS CSR row scan (ballot+shfl)
        float avl = 0.f;
        bool hit = false;
        for (int t = lane; t < dul; t += 64)
            if ((int)Aucol[t] == v) { avl = Auval[t]; hit = true; }
        unsigned long long hm = __ballot(hit);
        float av = hm ? __shfl(avl, (int)__builtin_ctzll(hm)) : 0.f;
        float adj;
        if (highD) {
            adj = (av != 0.f) ? (a2v - av) : 0.f;      // Z_high = (A==0)
        } else if (nz < 0) {
            adj = a2v - av;                             // nosparse: Z = false
        } else if (nz == 0) {
            adj = 0.f;                                  // all nbrs masked
        } else if (a2v == 0.f) {
            adj = 0.f;                                  // not a 2-hop nbr
        } else {
            // dv lookup among candidates (ballot+shfl)
            float dvl = 0.f; bool fnd = false;
            for (int c = lane; c < Drs; c += 64)
                if ((int)cidx[c] == v) { dvl = cdist[c]; fnd = true; }
            unsigned long long fm = __ballot(fnd);
            float dv = __shfl(dvl, (int)__builtin_ctzll(fm));
            // stable descending rank of v among candidates
            int cnt = 0;
            for (int c = lane; c < Drs; c += 64) {
                float cd = cdist[c];
                int ci = cidx[c];
                cnt += (cd > dv || (cd == dv && ci < v)) ? 1 : 0;
            }
            cnt = wred_sum(cnt);
            adj = (cnt < nz) ? 0.f : (a2v - av);
        }
        if (lane == 0) out[e] = fmaxf(0.f, fmaf(th1, w, th2 * adj));
    }
}

// ---------------------------------------------------------------------------
extern "C" void kernel_launch(void* const* d_in, const int* in_sizes, int n_in,
                              void* d_out, int out_size, void* d_ws, size_t ws_size,
                              hipStream_t stream) {
    const int* ei = (const int*)d_in[0];
    const float* ew = (const float*)d_in[1];
    const float* X = (const float*)d_in[2];
    const float* th1 = (const float*)d_in[3];
    const float* th2 = (const float*)d_in[4];
    float* out = (float*)d_out;

    char* ws = (char*)d_ws;
    size_t off = 0;
    unsigned short* ccol = (unsigned short*)(ws + off); off += (size_t)NN * MAXDEG * 2;
    float* cval = (float*)(ws + off);         off += (size_t)NN * MAXDEG * 4;
    int* deg = (int*)(ws + off);              off += (size_t)NN * 4;
    int* elist = (int*)(ws + off);            off += (size_t)NN * MAXEPR * 4;
    int* ecnt = (int*)(ws + off);             off += (size_t)NN * 4;
    double* sq = (double*)(ws + off);         off += (size_t)NN * 8;
    double* thres = (double*)(ws + off);      off += 256;

    hipMemsetAsync(ecnt, 0, (size_t)NN * 4, stream);

    k_scatter<<<EE / 256, 256, 0, stream>>>(ei, ecnt, elist);
    k_build<<<NN / 4, 256, 0, stream>>>(ei, ew, ecnt, elist, X, ccol, cval, deg, sq);
    k_stats<<<1, 256, 0, stream>>>(deg, thres);
    k_main<<<NN, 256, 0, stream>>>(ei, ew, X, th1, th2, ccol, cval, deg,
                                   ecnt, elist, sq, thres, out);
}

// Round 4
// 277.522 us; speedup vs baseline: 1.6203x; 1.6203x over previous
//
#include <hip/hip_runtime.h>

#define NN 4096
#define FF 256
#define EE 65536
#define MAXDEG 64
#define MAXEPR 256
#define NCAND 2048

__device__ __forceinline__ int wred_sum(int v) {
#pragma unroll
    for (int o = 32; o >= 1; o >>= 1) v += __shfl_xor(v, o);
    return v;
}

// ---------------------------------------------------------------------------
// K1: per-row edge-id lists only
// ---------------------------------------------------------------------------
__global__ void k_scatter(const int* __restrict__ ei, int* __restrict__ ecnt,
                          int* __restrict__ elist) {
    int e = blockIdx.x * blockDim.x + threadIdx.x;
    if (e >= EE) return;
    int r = ei[e];
    int p = atomicAdd(&ecnt[r], 1);
    if (p < MAXEPR) elist[r * MAXEPR + p] = e;
}

// ---------------------------------------------------------------------------
// K2: block-per-row CSR build via dense LDS row: scatter-add weights (dedups
// duplicates), clamp to 1, drop diagonal, ballot-compact. Also sq[row] (f64).
// ---------------------------------------------------------------------------
__global__ void k_build(const int* __restrict__ ei, const float* __restrict__ ew,
                        const int* __restrict__ ecnt, const int* __restrict__ elist,
                        const float* __restrict__ X,
                        unsigned short* __restrict__ ccol, float* __restrict__ cval,
                        int* __restrict__ deg, double* __restrict__ sq) {
    __shared__ float row[NN];
    __shared__ int cnt;
    const int u = blockIdx.x;
    const int tid = threadIdx.x;
    const int lane = tid & 63;
    const unsigned long long lmask = (1ull << lane) - 1ull;

    for (int i = tid; i < NN; i += 256) row[i] = 0.f;
    if (tid == 0) cnt = 0;
    __syncthreads();

    int ne = ecnt[u]; if (ne > MAXEPR) ne = MAXEPR;
    for (int i = tid; i < ne; i += 256) {
        int e = elist[u * MAXEPR + i];
        int c = ei[EE + e];
        if (c != u) atomicAdd(&row[c], ew[e]);   // diagonal gets zeroed anyway
    }
    __syncthreads();

    for (int i = tid; i < NN; i += 256) {
        float w = row[i];
        bool nzf = (w != 0.f);
        unsigned long long m = __ballot(nzf);
        int base = 0;
        if (lane == 0 && m) base = atomicAdd(&cnt, __popcll(m));
        base = __shfl(base, 0);
        int pos = base + __popcll(m & lmask);
        if (nzf && pos < MAXDEG) {
            ccol[u * MAXDEG + pos] = (unsigned short)i;
            cval[u * MAXDEG + pos] = fminf(w, 1.f);
        }
    }
    __syncthreads();
    if (tid == 0) deg[u] = cnt;

    if (tid < 64) {
        float4 x4 = ((const float4*)(X + (size_t)u * FF))[lane];
        double s = (double)x4.x * x4.x + (double)x4.y * x4.y +
                   (double)x4.z * x4.z + (double)x4.w * x4.w;
#pragma unroll
        for (int o = 32; o >= 1; o >>= 1) s += __shfl_xor(s, o);
        if (lane == 0) sq[u] = s;
    }
}

// ---------------------------------------------------------------------------
// K3: d_thres = mean(deg) + 2*std(deg), single block
// ---------------------------------------------------------------------------
__global__ void k_stats(const int* __restrict__ deg, double* __restrict__ thres) {
    __shared__ double sd[256], sd2[256];
    int t = threadIdx.x;
    double s = 0, s2 = 0;
    for (int i = t; i < NN; i += 256) {
        double d = (double)deg[i];
        s += d; s2 += d * d;
    }
    sd[t] = s; sd2[t] = s2;
    __syncthreads();
    for (int o = 128; o >= 1; o >>= 1) {
        if (t < o) { sd[t] += sd[t + o]; sd2[t] += sd2[t + o]; }
        __syncthreads();
    }
    if (t == 0) {
        double mean = sd[0] / NN;
        double var = sd2[0] / NN - mean * mean;
        if (var < 0) var = 0;
        thres[0] = mean + 2.0 * sqrt(var);
    }
}

// ---------------------------------------------------------------------------
// K4: per-row main kernel
// ---------------------------------------------------------------------------
__launch_bounds__(256, 5)
__global__ void k_main(const int* __restrict__ ei, const float* __restrict__ ew,
                       const float* __restrict__ X, const float* __restrict__ th1p,
                       const float* __restrict__ th2p,
                       const unsigned short* __restrict__ ccol,
                       const float* __restrict__ cval, const int* __restrict__ deg,
                       const int* __restrict__ ecnt, const int* __restrict__ elist,
                       const double* __restrict__ sq, const double* __restrict__ thresp,
                       float* __restrict__ out) {
    __shared__ float acc[NN];              // A2 row values (16KB)
    __shared__ float Xu[FF];               // 1KB
    __shared__ unsigned short cidx[NCAND]; // 4KB
    __shared__ float cdist[NCAND];         // 8KB
    __shared__ unsigned short Aucol[MAXDEG];
    __shared__ float Auval[MAXDEG];
    __shared__ int ncand;

    const int u = blockIdx.x;
    const int tid = threadIdx.x;
    const int lane = tid & 63;
    const int wave = tid >> 6;
    const unsigned long long lmask = (1ull << lane) - 1ull;

    const int du = deg[u];
    const int dul = min(du, MAXDEG);
    for (int i = tid; i < NN; i += 256) acc[i] = 0.f;
    if (tid < FF / 4)
        ((float4*)Xu)[tid] = ((const float4*)(X + (size_t)u * FF))[tid];
    if (tid >= 128 && tid - 128 < dul) {
        Aucol[tid - 128] = ccol[u * MAXDEG + tid - 128];
        Auval[tid - 128] = cval[u * MAXDEG + tid - 128];
    }
    if (tid == 0) ncand = 0;
    __syncthreads();

    // --- build A2 row: A' = A + I; acc[v] += A'[u][k]*A'[k][v] ---
    for (int kk = wave; kk <= dul; kk += 4) {
        int k; float wuk;
        if (kk == dul) { k = u; wuk = 1.f; }           // self term A'[u][u]=1
        else { k = Aucol[kk]; wuk = Auval[kk]; }
        int dkl = min(deg[k], MAXDEG);
        for (int j = lane; j <= dkl; j += 64) {
            int v; float wkv;
            if (j == dkl) { v = k; wkv = 1.f; }        // self term A'[k][k]=1
            else { v = ccol[k * MAXDEG + j]; wkv = cval[k * MAXDEG + j]; }
            atomicAdd(&acc[v], wuk * wkv);
        }
    }
    __syncthreads();
    if (tid == 0) acc[u] = 0.f;                        // zero diag of A2
    __syncthreads();

    // --- compact 2-hop candidates (ballot-aggregated) ---
    for (int i = tid; i < NN; i += 256) {
        bool nzf = (acc[i] != 0.f);
        unsigned long long m = __ballot(nzf);
        int base = 0;
        if (lane == 0 && m) base = atomicAdd(&ncand, __popcll(m));
        base = __shfl(base, 0);
        int pos = base + __popcll(m & lmask);
        if (nzf && pos < NCAND) cidx[pos] = (unsigned short)i;
    }
    __syncthreads();
    const int Dr = ncand;
    const int Drs = min(Dr, NCAND);

    // --- distances: one candidate per THREAD (R2-proven pattern), f64 dot ---
    const double squ = sq[u];
    for (int c = tid; c < Drs; c += 256) {
        int v = cidx[c];
        const float4* __restrict__ Xv = (const float4*)(X + (size_t)v * FF);
        double sqv = sq[v];
        double s0 = 0, s1 = 0, s2 = 0, s3 = 0;
#pragma unroll 2
        for (int f = 0; f < FF / 4; f += 4) {
            float4 a0 = Xv[f + 0], a1 = Xv[f + 1], a2 = Xv[f + 2], a3 = Xv[f + 3];
            float4 b0 = ((const float4*)Xu)[f + 0];
            float4 b1 = ((const float4*)Xu)[f + 1];
            float4 b2 = ((const float4*)Xu)[f + 2];
            float4 b3 = ((const float4*)Xu)[f + 3];
            s0 += (double)a0.x * b0.x + (double)a0.y * b0.y +
                  (double)a0.z * b0.z + (double)a0.w * b0.w;
            s1 += (double)a1.x * b1.x + (double)a1.y * b1.y +
                  (double)a1.z * b1.z + (double)a1.w * b1.w;
            s2 += (double)a2.x * b2.x + (double)a2.y * b2.y +
                  (double)a2.z * b2.z + (double)a2.w * b2.w;
            s3 += (double)a3.x * b3.x + (double)a3.y * b3.y +
                  (double)a3.z * b3.z + (double)a3.w * b3.w;
        }
        cdist[c] = (float)(squ + sqv - 2.0 * (s0 + s1 + s2 + s3));
    }
    __syncthreads();

    // --- per-edge output: one WAVE per edge ---
    const int D = du;
    const bool highD = ((double)D > thresp[0]);
    const int nz = Dr - 2 * D;                         // nz_sel
    const float th1 = th1p[0], th2 = th2p[0];
    int ne = ecnt[u]; if (ne > MAXEPR) ne = MAXEPR;
    for (int idx = wave; idx < ne; idx += 4) {
        int e = elist[u * MAXEPR + idx];
        int v = ei[EE + e];                            // wave-uniform
        float w = ew[e];
        float a2v = acc[v];
        // av = A[u][v] via LDS CSR row scan (ballot+shfl)
        float avl = 0.f;
        bool hit = false;
        for (int t = lane; t < dul; t += 64)
            if ((int)Aucol[t] == v) { avl = Auval[t]; hit = true; }
        unsigned long long hm = __ballot(hit);
        float av = hm ? __shfl(avl, (int)__builtin_ctzll(hm)) : 0.f;
        float adj;
        if (highD) {
            adj = (av != 0.f) ? (a2v - av) : 0.f;      // Z_high = (A==0)
        } else if (nz < 0) {
            adj = a2v - av;                             // nosparse: Z = false
        } else if (nz == 0) {
            adj = 0.f;                                  // all nbrs masked
        } else if (a2v == 0.f) {
            adj = 0.f;                                  // not a 2-hop nbr (A subset A2)
        } else {
            // dv lookup among candidates (ballot+shfl)
            float dvl = 0.f; bool fnd = false;
            for (int c = lane; c < Drs; c += 64)
                if ((int)cidx[c] == v) { dvl = cdist[c]; fnd = true; }
            unsigned long long fm = __ballot(fnd);
            float dv = __shfl(dvl, (int)__builtin_ctzll(fm));
            // stable descending rank of v among candidates
            int cnt = 0;
            for (int c = lane; c < Drs; c += 64) {
                float cd = cdist[c];
                int ci = cidx[c];
                cnt += (cd > dv || (cd == dv && ci < v)) ? 1 : 0;
            }
            cnt = wred_sum(cnt);
            adj = (cnt < nz) ? 0.f : (a2v - av);
        }
        if (lane == 0) out[e] = fmaxf(0.f, fmaf(th1, w, th2 * adj));
    }
}

// ---------------------------------------------------------------------------
extern "C" void kernel_launch(void* const* d_in, const int* in_sizes, int n_in,
                              void* d_out, int out_size, void* d_ws, size_t ws_size,
                              hipStream_t stream) {
    const int* ei = (const int*)d_in[0];
    const float* ew = (const float*)d_in[1];
    const float* X = (const float*)d_in[2];
    const float* th1 = (const float*)d_in[3];
    const float* th2 = (const float*)d_in[4];
    float* out = (float*)d_out;

    char* ws = (char*)d_ws;
    size_t off = 0;
    unsigned short* ccol = (unsigned short*)(ws + off); off += (size_t)NN * MAXDEG * 2;
    float* cval = (float*)(ws + off);         off += (size_t)NN * MAXDEG * 4;
    int* deg = (int*)(ws + off);              off += (size_t)NN * 4;
    int* ecnt = (int*)(ws + off);             off += (size_t)NN * 4;
    double* sq = (double*)(ws + off);         off += (size_t)NN * 8;
    double* thres = (double*)(ws + off);      off += 256;
    int* elist = (int*)(ws + off);            off += (size_t)NN * MAXEPR * 4;

    hipMemsetAsync(ecnt, 0, (size_t)NN * 4, stream);

    k_scatter<<<EE / 256, 256, 0, stream>>>(ei, ecnt, elist);
    k_build<<<NN, 256, 0, stream>>>(ei, ew, ecnt, elist, X, ccol, cval, deg, sq);
    k_stats<<<1, 256, 0, stream>>>(deg, thres);
    k_main<<<NN, 256, 0, stream>>>(ei, ew, X, th1, th2, ccol, cval, deg,
                                   ecnt, elist, sq, thres, out);
}